// Round 14
// baseline (162.015 us; speedup 1.0000x reference)
//
#include <hip/hip_runtime.h>
#include <hip/hip_cooperative_groups.h>

namespace cg = cooperative_groups;

constexpr int NPIX  = 1 << 20;      // 1024*1024 pixels
constexpr int NCLS  = 21;
constexpr int NBINS = 480;          // linear bins over [0,8): width = 1/60
constexpr float RANGE = 8.0f;
constexpr float BIN_SCALE = NBINS / RANGE;   // 60
constexpr int NBLK = 512;           // 2 blocks/CU guaranteed (coop co-residency)
constexpr int NTHR = 512;
constexpr int QPC  = NPIX / 4;      // 262144 quads per class (2^18)
constexpr int TQ   = NCLS * QPC;    // 5,505,024 flat (class,quad) indices
constexpr int QPB  = TQ / NBLK;     // 10752 quads per block (exact)

typedef int   iv4 __attribute__((ext_vector_type(4)));
typedef float fv4 __attribute__((ext_vector_type(4)));

// ---------------------------------------------------------------------------
// ONE cooperative kernel, three phases, two grid.sync()s — no launch gaps.
//  P1: per-pixel argmax (1 quad/thread, 512x512 = NPIX/4 exactly)
//  P2: histogram over flat (class,quad) ranges; each block's contiguous
//      10752-quad range spans <=2 classes -> 2 LDS hists (3.84 KB),
//      u64-atomic flush into the global per-class histogram
//  P3: per-class descending shuffle-scan + Lovasz dot + mean (blocks 0..20)
// ---------------------------------------------------------------------------
__global__ void __launch_bounds__(NTHR, 4)
k_coop(const iv4* __restrict__ label4, const fv4* __restrict__ pred4,
       uchar4* __restrict__ lbl, unsigned long long* __restrict__ hist,
       float* __restrict__ out) {
    cg::grid_group grid = cg::this_grid();
    const int b = blockIdx.x;
    const int t = threadIdx.x;

    __shared__ unsigned int sh[2 * NBINS];             // 3.84 KB
    __shared__ unsigned int swn[8], swf[8];
    __shared__ double sd[8];

    // ---- phase 0: zero global hist (first blocks) & out[0]
    {
        int idx = b * NTHR + t;
        if (idx < NCLS * NBINS) hist[idx] = 0ULL;
        if (idx == 0) out[0] = 0.0f;
    }

    // ---- phase 1: argmax (strict > keeps FIRST max, like jnp.argmax)
    {
        const int q = b * NTHR + t;                    // exactly NPIX/4 threads
        iv4 best = label4[q];
        int bx = 0, by = 0, bz = 0, bw = 0;
        #pragma unroll
        for (int c = 1; c < NCLS; ++c) {
            iv4 v = label4[(size_t)c * QPC + q];
            if (v.x > best.x) { best.x = v.x; bx = c; }
            if (v.y > best.y) { best.y = v.y; by = c; }
            if (v.z > best.z) { best.z = v.z; bz = c; }
            if (v.w > best.w) { best.w = v.w; bw = c; }
        }
        lbl[q] = make_uchar4((unsigned char)bx, (unsigned char)by,
                             (unsigned char)bz, (unsigned char)bw);
    }
    grid.sync();

    // ---- phase 2: histogram (balanced flat ranges, single-phase stream)
    {
        for (int k = t; k < 2 * NBINS; k += NTHR) sh[k] = 0u;
        __syncthreads();

        const int start = b * QPB;
        const int c0 = start >> 18;                    // first class in range
        for (int k = t; k < QPB; k += NTHR) {          // 21 iterations/thread
            int qg = start + k;
            int c  = qg >> 18;                         // QPC = 2^18
            int i4 = qg & (QPC - 1);
            fv4 p    = pred4[qg];
            uchar4 l = lbl[i4];
            unsigned int* shc = sh + (c - c0) * NBINS;
            {
                unsigned int fg = (l.x == c) ? 1u : 0u;
                float e = fabsf((float)fg - p.x);
                int bin = (int)(e * BIN_SCALE); bin = bin < NBINS-1 ? bin : NBINS-1;
                atomicAdd(&shc[bin], 1u | (fg << 16));
            }
            {
                unsigned int fg = (l.y == c) ? 1u : 0u;
                float e = fabsf((float)fg - p.y);
                int bin = (int)(e * BIN_SCALE); bin = bin < NBINS-1 ? bin : NBINS-1;
                atomicAdd(&shc[bin], 1u | (fg << 16));
            }
            {
                unsigned int fg = (l.z == c) ? 1u : 0u;
                float e = fabsf((float)fg - p.z);
                int bin = (int)(e * BIN_SCALE); bin = bin < NBINS-1 ? bin : NBINS-1;
                atomicAdd(&shc[bin], 1u | (fg << 16));
            }
            {
                unsigned int fg = (l.w == c) ? 1u : 0u;
                float e = fabsf((float)fg - p.w);
                int bin = (int)(e * BIN_SCALE); bin = bin < NBINS-1 ? bin : NBINS-1;
                atomicAdd(&shc[bin], 1u | (fg << 16));
            }
        }
        __syncthreads();

        // flush: one u64 atomic per non-empty (class,bin)
        for (int k = t; k < 2 * NBINS; k += NTHR) {
            unsigned int v = sh[k];
            if (v) {
                int c   = c0 + (k >= NBINS ? 1 : 0);
                int bin = k - (k >= NBINS ? NBINS : 0);
                if (c < NCLS) {
                    unsigned long long add =
                        (unsigned long long)(v & 0xFFFFu) |
                        ((unsigned long long)(v >> 16) << 32);
                    atomicAdd(&hist[(size_t)c * NBINS + bin], add);
                }
            }
        }
    }
    grid.sync();

    // ---- phase 3: per-class scan + Lovasz dot + mean (blocks 0..20)
    if (b < NCLS) {
        const int c    = b;
        const int lane = t & 63;
        const int wv   = t >> 6;                       // 8 waves

        const int bin = NBINS - 1 - t;                 // valid when t < NBINS
        unsigned int tn = 0, tf = 0;
        if (t < NBINS) {
            unsigned long long v = hist[(size_t)c * NBINS + bin];
            tn = (unsigned int)v;
            tf = (unsigned int)(v >> 32);
        }

        unsigned int in_ = tn, if_ = tf;
        #pragma unroll
        for (int off = 1; off < 64; off <<= 1) {
            unsigned int an = __shfl_up(in_, off, 64);
            unsigned int af = __shfl_up(if_, off, 64);
            if (lane >= off) { in_ += an; if_ += af; }
        }

        if (lane == 63) { swn[wv] = in_; swf[wv] = if_; }
        __syncthreads();

        if (wv == 0 && lane < 8) {                     // scan the 8 wave totals
            unsigned int a = swn[lane], bb = swf[lane];
            #pragma unroll
            for (int off = 1; off < 8; off <<= 1) {
                unsigned int an = __shfl_up(a, off, 64);
                unsigned int af = __shfl_up(bb, off, 64);
                if (lane >= off) { a += an; bb += af; }
            }
            swn[lane] = a; swf[lane] = bb;             // inclusive wave prefixes
        }
        __syncthreads();

        const unsigned int G = swf[7];                 // total foreground count
        unsigned int i = in_ - tn + (wv ? swn[wv - 1] : 0u);   // exclusive prefix
        unsigned int F = if_ - tf + (wv ? swf[wv - 1] : 0u);

        double acc = 0.0;
        if (tn) {
            double jprev = (i > 0) ? (double)i / (double)(G + i - F) : 0.0;
            unsigned int i2 = i + tn, F2 = F + tf;
            double jhi = (double)i2 / (double)(G + i2 - F2);
            acc = ((bin + 0.5) * (double)(RANGE / NBINS)) * (jhi - jprev);
        }

        #pragma unroll
        for (int off = 32; off > 0; off >>= 1) acc += __shfl_down(acc, off, 64);
        if (lane == 0) sd[wv] = acc;
        __syncthreads();
        if (t == 0) {
            double s = 0.0;
            #pragma unroll
            for (int k = 0; k < 8; ++k) s += sd[k];
            atomicAdd(out, (float)(s / NCLS));
        }
    }
}

extern "C" void kernel_launch(void* const* d_in, const int* in_sizes, int n_in,
                              void* d_out, int out_size, void* d_ws, size_t ws_size,
                              hipStream_t stream) {
    const fv4* pred4  = (const fv4*)d_in[0];
    const iv4* label4 = (const iv4*)d_in[1];
    float* out = (float*)d_out;

    char* ws = (char*)d_ws;
    uchar4* lbl = (uchar4*)ws;                                   // 1 MB
    unsigned long long* hist = (unsigned long long*)(ws + (size_t)NPIX); // 80.6 KB

    void* args[] = { (void*)&label4, (void*)&pred4, (void*)&lbl,
                     (void*)&hist, (void*)&out };
    hipLaunchCooperativeKernel((void*)k_coop, dim3(NBLK), dim3(NTHR),
                               args, 0, stream);
}

// Round 15
// 37.306 us; speedup vs baseline: 4.3429x; 4.3429x over previous
//
#include <hip/hip_runtime.h>

constexpr int NPIX  = 1 << 20;      // 1024*1024 pixels
constexpr int NCLS  = 21;
constexpr int NBINS = 240;          // linear bins over [0,8): width = 1/30
constexpr float RANGE = 8.0f;
constexpr float BIN_SCALE = NBINS / RANGE;   // 30
constexpr int NCHUNK = 32;
constexpr int CHUNK_PIX = NPIX / NCHUNK;     // 32768 (fits u16 bin counts)

typedef int   iv4 __attribute__((ext_vector_type(4)));
typedef float fv4 __attribute__((ext_vector_type(4)));

// ---------------------------------------------------------------------------
// 1) per-pixel argmax (single-phase label stream, ~6 TB/s).
//    int4 loads, uchar4 result (1 MB -> L2-resident for k_hist's re-reads).
//    Block 0 also zeroes the global hist (40.3 KB) and out[0].
// ---------------------------------------------------------------------------
__global__ void k_argmax(const iv4* __restrict__ label4, uchar4* __restrict__ lbl,
                         unsigned long long* __restrict__ hist,
                         float* __restrict__ out) {
    int i = blockIdx.x * blockDim.x + threadIdx.x;     // over NPIX/4
    if (blockIdx.x == 0) {
        for (int b = threadIdx.x; b < NCLS * NBINS; b += blockDim.x)
            hist[b] = 0ULL;
        if (threadIdx.x == 0) out[0] = 0.0f;
    }
    if (i >= NPIX / 4) return;
    iv4 best = label4[i];
    int bx = 0, by = 0, bz = 0, bw = 0;
    #pragma unroll
    for (int c = 1; c < NCLS; ++c) {
        iv4 v = label4[(size_t)c * (NPIX / 4) + i];
        if (v.x > best.x) { best.x = v.x; bx = c; }    // strict > keeps FIRST max
        if (v.y > best.y) { best.y = v.y; by = c; }
        if (v.z > best.z) { best.z = v.z; bz = c; }
        if (v.w > best.w) { best.w = v.w; bw = c; }
    }
    lbl[i] = make_uchar4((unsigned char)bx, (unsigned char)by,
                         (unsigned char)bz, (unsigned char)bw);
}

// ---------------------------------------------------------------------------
// 2) per-(chunk, class) histogram with 4-WAY REPLICATED LDS sub-histograms
//    (copy = lane&3) to cut same-bin atomic serialization 4x. 8 pixels per
//    thread-iteration (2 fv4 + 1 uint2 label load -> 3 loads in flight).
//    Flush: sum 4 packed copies (n|fg<<16; sums fit u16 fields since
//    chunk = 32768 <= 65535), one u64 global atomic per bin into final hist.
// ---------------------------------------------------------------------------
__global__ void __launch_bounds__(512)
k_hist(const fv4* __restrict__ pred4, const uint2* __restrict__ lbl8,
       unsigned long long* __restrict__ hist) {
    __shared__ unsigned int sh[4][NBINS];              // 3.75 KB
    const int chunk = blockIdx.x;
    const int c     = blockIdx.y;
    const int t     = threadIdx.x;
    const int cp    = t & 3;

    for (int b = t; b < 4 * NBINS; b += 512) sh[b / NBINS][b % NBINS] = 0u;
    __syncthreads();

    const size_t pbase4 = ((size_t)c * NPIX + (size_t)chunk * CHUNK_PIX) / 4;
    const size_t lbase8 = ((size_t)chunk * CHUNK_PIX) / 8;
    constexpr int NPAIR = CHUNK_PIX / 8;               // 4096 quad-pairs

    #pragma unroll 2
    for (int k = t; k < NPAIR; k += 512) {
        fv4 p0 = pred4[pbase4 + 2 * k];
        fv4 p1 = pred4[pbase4 + 2 * k + 1];
        uint2 lw = lbl8[lbase8 + k];                   // 8 packed uchar labels
        unsigned int la = lw.x, lb = lw.y;

        float pe[8] = { p0.x, p0.y, p0.z, p0.w, p1.x, p1.y, p1.z, p1.w };
        unsigned int lc[8] = { la & 0xFFu, (la >> 8) & 0xFFu,
                               (la >> 16) & 0xFFu, la >> 24,
                               lb & 0xFFu, (lb >> 8) & 0xFFu,
                               (lb >> 16) & 0xFFu, lb >> 24 };
        #pragma unroll
        for (int j = 0; j < 8; ++j) {
            unsigned int fg = (lc[j] == (unsigned int)c) ? 1u : 0u;
            float e = fabsf((float)fg - pe[j]);
            int bin = (int)(e * BIN_SCALE);
            bin = bin < NBINS - 1 ? bin : NBINS - 1;
            atomicAdd(&sh[cp][bin], 1u | (fg << 16));
        }
    }
    __syncthreads();

    // flush: packed sum of the 4 copies, one u64 atomic per non-empty bin
    for (int b = t; b < NBINS; b += 512) {
        unsigned int v = sh[0][b] + sh[1][b] + sh[2][b] + sh[3][b];
        if (v) {
            unsigned long long add =
                (unsigned long long)(v & 0xFFFFu) |
                ((unsigned long long)(v >> 16) << 32);
            atomicAdd(&hist[(size_t)c * NBINS + b], add);
        }
    }
}

// ---------------------------------------------------------------------------
// 3) per-class descending scan + Lovasz dot + mean: one block per class
//    (256 threads, 4 waves); thread t owns descending rank t (bin NBINS-1-t);
//    shuffle-scan, then one atomicAdd of loss_c/NCLS into out[0].
// ---------------------------------------------------------------------------
__global__ void __launch_bounds__(256)
k_scanfinal(const unsigned long long* __restrict__ hist, float* __restrict__ out) {
    const int c    = blockIdx.x;
    const int t    = threadIdx.x;
    const int lane = t & 63;
    const int wv   = t >> 6;                           // 4 waves

    const int bin = NBINS - 1 - t;                     // valid when t < NBINS
    unsigned int tn = 0, tf = 0;
    if (t < NBINS) {
        unsigned long long v = hist[(size_t)c * NBINS + bin];
        tn = (unsigned int)v;
        tf = (unsigned int)(v >> 32);
    }

    // wave-inclusive scan of (tn, tf)
    unsigned int in_ = tn, if_ = tf;
    #pragma unroll
    for (int off = 1; off < 64; off <<= 1) {
        unsigned int an = __shfl_up(in_, off, 64);
        unsigned int af = __shfl_up(if_, off, 64);
        if (lane >= off) { in_ += an; if_ += af; }
    }

    __shared__ unsigned int swn[4], swf[4];
    if (lane == 63) { swn[wv] = in_; swf[wv] = if_; }
    __syncthreads();

    if (wv == 0 && lane < 4) {                         // scan the 4 wave totals
        unsigned int a = swn[lane], b = swf[lane];
        #pragma unroll
        for (int off = 1; off < 4; off <<= 1) {
            unsigned int an = __shfl_up(a, off, 64);
            unsigned int af = __shfl_up(b, off, 64);
            if (lane >= off) { a += an; b += af; }
        }
        swn[lane] = a; swf[lane] = b;                  // inclusive wave prefixes
    }
    __syncthreads();

    const unsigned int G = swf[3];                     // total foreground count
    unsigned int i = in_ - tn + (wv ? swn[wv - 1] : 0u);   // exclusive prefix
    unsigned int F = if_ - tf + (wv ? swf[wv - 1] : 0u);

    double acc = 0.0;
    if (tn) {
        double jprev = (i > 0) ? (double)i / (double)(G + i - F) : 0.0;
        unsigned int i2 = i + tn, F2 = F + tf;
        double jhi = (double)i2 / (double)(G + i2 - F2);
        acc = ((bin + 0.5) * (double)(RANGE / NBINS)) * (jhi - jprev);
    }

    // block reduce, then one atomicAdd per class
    #pragma unroll
    for (int off = 32; off > 0; off >>= 1) acc += __shfl_down(acc, off, 64);
    __shared__ double sd[4];
    if (lane == 0) sd[wv] = acc;
    __syncthreads();
    if (t == 0) {
        double s = sd[0] + sd[1] + sd[2] + sd[3];
        atomicAdd(out, (float)(s / NCLS));
    }
}

extern "C" void kernel_launch(void* const* d_in, const int* in_sizes, int n_in,
                              void* d_out, int out_size, void* d_ws, size_t ws_size,
                              hipStream_t stream) {
    const float* pred  = (const float*)d_in[0];
    const int*   label = (const int*)d_in[1];
    float* out = (float*)d_out;

    char* ws = (char*)d_ws;
    unsigned char* lbl = (unsigned char*)ws;                     // 1 MB
    size_t off = (size_t)NPIX;
    unsigned long long* hist = (unsigned long long*)(ws + off);  // 40.3 KB

    k_argmax<<<NPIX / 4 / 256, 256, 0, stream>>>((const iv4*)label, (uchar4*)lbl,
                                                 hist, out);
    dim3 hgrid(NCHUNK, NCLS);
    k_hist<<<hgrid, 512, 0, stream>>>((const fv4*)pred, (const uint2*)lbl, hist);
    k_scanfinal<<<NCLS, 256, 0, stream>>>(hist, out);
}